// Round 14
// baseline (184.416 us; speedup 1.0000x reference)
//
#include <hip/hip_runtime.h>
#include <hip/hip_bf16.h>
#include <hip/hip_fp16.h>

#define H_FEATS 128
#define HIDDEN  32
#define BUCKET_SHIFT 7            // 128 nodes/bucket -> ~782 buckets (subsort parallelism)
#define NB (1 << BUCKET_SHIFT)    // nodes per bucket
#define MAX_BUCKETS 1024
#define SORT_EPB 4096             // edges per block in sort passes

typedef _Float16 f16x8 __attribute__((ext_vector_type(8)));
typedef float    f32x4 __attribute__((ext_vector_type(4)));

union H8 { uint4 u; __half2 h2[4]; };
union U16 { uint4 u; f16x8 h; };

// ---- device helpers for prep work ----
__device__ __forceinline__ void do_convert_h(
    const float* __restrict__ h, __half* __restrict__ hh, int i, int n8)
{
    if (i >= n8) return;
    const float4* s = reinterpret_cast<const float4*>(h) + (size_t)i * 2;
    float4 a = s[0], b = s[1];
    H8 r;
    r.h2[0] = __floats2half2_rn(a.x, a.y);
    r.h2[1] = __floats2half2_rn(a.z, a.w);
    r.h2[2] = __floats2half2_rn(b.x, b.y);
    r.h2[3] = __floats2half2_rn(b.z, b.w);
    reinterpret_cast<uint4*>(hh)[i] = r.u;
}

// ---- Fused prep: convert_h | convert_w | per-block histogram ----
__global__ __launch_bounds__(256) void prep_fused_kernel(
    const float* __restrict__ h, __half* __restrict__ hh, int n8,
    const float* __restrict__ W1, __half* __restrict__ w1t,
    const int* __restrict__ src, int* __restrict__ blockhist,
    int n_edges, int nbuck, int hb, int cb, int wb)
{
    __shared__ int lh[MAX_BUCKETS];
    int bid = blockIdx.x;
    int tid = threadIdx.x;

    if (bid < cb) {
        do_convert_h(h, hh, bid * 256 + tid, n8);
        return;
    }
    bid -= cb;
    if (bid < wb) {
        int t = bid * 256 + tid;
        if (t < H_FEATS * HIDDEN) {
            int k = t >> 5, n = t & 31;
            w1t[(size_t)n * H_FEATS + k] = __float2half(W1[t]);
        }
        return;
    }
    bid -= wb;
    // histogram block
    for (int i = tid; i < nbuck; i += 256) lh[i] = 0;
    __syncthreads();
    int ebase = bid * SORT_EPB;
#pragma unroll
    for (int k = 0; k < SORT_EPB / 256; ++k) {
        int e = ebase + k * 256 + tid;
        if (e < n_edges) atomicAdd(&lh[src[e] >> BUCKET_SHIFT], 1);  // LDS atomic
    }
    __syncthreads();
    for (int i = tid; i < nbuck; i += 256)
        blockhist[(size_t)i * hb + bid] = lh[i];
}

// ---- standalone convert (fallback paths) ----
__global__ __launch_bounds__(256) void convert_h_kernel(
    const float* __restrict__ h, __half* __restrict__ hh, int n8)
{
    do_convert_h(h, hh, blockIdx.x * blockDim.x + threadIdx.x, n8);
}

// ---- Sort pass B1: exclusive scan each bucket-row across blocks ----
__global__ __launch_bounds__(256) void scan_rows_kernel(
    int* __restrict__ blockhist, int* __restrict__ rowsum, int nblocks)
{
    __shared__ int tmp[256];
    int row = blockIdx.x;
    int tid = threadIdx.x;
    size_t rowbase = (size_t)row * nblocks;
    int carry = 0;
    for (int c = 0; c < nblocks; c += 256) {
        int idx = c + tid;
        int v = (idx < nblocks) ? blockhist[rowbase + idx] : 0;
        tmp[tid] = v;
        __syncthreads();
#pragma unroll
        for (int d = 1; d < 256; d <<= 1) {
            int t = (tid >= d) ? tmp[tid - d] : 0;
            __syncthreads();
            tmp[tid] += t;
            __syncthreads();
        }
        int incl = tmp[tid];
        if (idx < nblocks) blockhist[rowbase + idx] = carry + incl - v;
        carry += tmp[255];
        __syncthreads();
    }
    if (tid == 0) rowsum[row] = carry;
}

// ---- Sort pass B2: exclusive scan of bucket totals -> base ----
__global__ __launch_bounds__(MAX_BUCKETS) void scan_base_kernel(
    const int* __restrict__ rowsum, int* __restrict__ base, int nbuck)
{
    __shared__ int tmp[MAX_BUCKETS];
    int tid = threadIdx.x;
    int v = (tid < nbuck) ? rowsum[tid] : 0;
    tmp[tid] = v;
    __syncthreads();
#pragma unroll
    for (int d = 1; d < MAX_BUCKETS; d <<= 1) {
        int t = (tid >= d) ? tmp[tid - d] : 0;
        __syncthreads();
        tmp[tid] += t;
        __syncthreads();
    }
    if (tid < nbuck) base[tid] = tmp[tid] - v;
}

// ---- Sort pass C: place edges into bucket order (no global atomics) ----
__global__ __launch_bounds__(256) void scatter_kernel(
    const int* __restrict__ src, const int* __restrict__ dst,
    const int* __restrict__ blockhist, const int* __restrict__ base,
    int2* __restrict__ spair, int* __restrict__ seid,
    int n_edges, int nbuck, int nblocks)
{
    __shared__ int lcur[MAX_BUCKETS];
    int tid = threadIdx.x;
    for (int i = tid; i < nbuck; i += 256)
        lcur[i] = base[i] + blockhist[(size_t)i * nblocks + blockIdx.x];
    __syncthreads();
    int ebase = blockIdx.x * SORT_EPB;
#pragma unroll
    for (int k = 0; k < SORT_EPB / 256; ++k) {
        int e = ebase + k * 256 + tid;
        if (e < n_edges) {
            int s = src[e];
            int p = atomicAdd(&lcur[s >> BUCKET_SHIFT], 1);   // LDS atomic
            spair[p] = make_int2(s, dst[e]);
            seid[p] = e;
        }
    }
}

// ---- Sort pass D: per-bucket counting sort by low BUCKET_SHIFT bits ->
// full per-node src order. One block per bucket (~782 blocks, ~2050 edges
// each). Full sort makes consecutive edges share src (mean degree 16 ==
// MFMA group size) -> m-lanes gather ~1-2 distinct src rows; TA coalesces
// identical addresses (r13: MLP 127 -> 97.5us).
__global__ __launch_bounds__(256) void subsort_kernel(
    const int2* __restrict__ spair1, const int* __restrict__ seid1,
    const int* __restrict__ base, const int* __restrict__ rowsum,
    int2* __restrict__ spair2, int* __restrict__ seid2)
{
    __shared__ int lh[NB];
    __shared__ int lcur[NB];
    __shared__ int tmp[256];
    int b = blockIdx.x;
    int tid = threadIdx.x;
    int start = base[b];
    int cnt = rowsum[b];

    if (tid < NB) lh[tid] = 0;
    __syncthreads();
    for (int i = tid; i < cnt; i += 256)
        atomicAdd(&lh[spair1[start + i].x & (NB - 1)], 1);
    __syncthreads();

    // exclusive scan of NB (<=256) with guarded Hillis-Steele
    int v = (tid < NB) ? lh[tid] : 0;
    tmp[tid] = v;
    __syncthreads();
#pragma unroll
    for (int d = 1; d < NB; d <<= 1) {
        int t = (tid >= d) ? tmp[tid - d] : 0;
        __syncthreads();
        tmp[tid] += t;
        __syncthreads();
    }
    if (tid < NB) lcur[tid] = tmp[tid] - v;
    __syncthreads();

    for (int i = tid; i < cnt; i += 256) {
        int2 sp = spair1[start + i];
        int sid = seid1[start + i];
        int p = atomicAdd(&lcur[sp.x & (NB - 1)], 1);   // LDS atomic
        spair2[start + p] = sp;
        seid2[start + p] = sid;
    }
}

// ---- MFMA MLP helpers (arrays with compile-time indices only) ----
__device__ __forceinline__ void issue_g(
    const __half* __restrict__ hh, int2 sp, int koff, U16 (&A)[4], U16 (&B)[4])
{
    const __half* hs = hh + (size_t)sp.x * H_FEATS;
    const __half* hd = hh + (size_t)sp.y * H_FEATS;
#pragma unroll
    for (int s = 0; s < 4; ++s) {
        A[s].u = *reinterpret_cast<const uint4*>(hs + s * 32 + koff);
        B[s].u = *reinterpret_cast<const uint4*>(hd + s * 32 + koff);
    }
}

__device__ __forceinline__ void compute_g(
    U16 (&A)[4], U16 (&B)[4], const f16x8 (&w1frag)[2][4],
    const float* b1lop, const float* b1hip, const float* w2lop, const float* w2hip,
    float b2f, int kq, int sid, bool eok, float* __restrict__ out)
{
    f32x4 acc0 = {0.f, 0.f, 0.f, 0.f};
    f32x4 acc1 = {0.f, 0.f, 0.f, 0.f};
#pragma unroll
    for (int s = 0; s < 4; ++s) {
        f16x8 he = A[s].h * B[s].h;
        acc0 = __builtin_amdgcn_mfma_f32_16x16x32_f16(w1frag[0][s], he, acc0, 0, 0, 0);
        acc1 = __builtin_amdgcn_mfma_f32_16x16x32_f16(w1frag[1][s], he, acc1, 0, 0, 0);
    }
    float p = 0.f;
#pragma unroll
    for (int r = 0; r < 4; ++r) {
        float h0 = acc0[r] + b1lop[r]; h0 = h0 > 0.f ? h0 : 0.f;
        float h1 = acc1[r] + b1hip[r]; h1 = h1 > 0.f ? h1 : 0.f;
        p = fmaf(h0, w2lop[r], p);
        p = fmaf(h1, w2hip[r], p);
    }
    p += __shfl_xor(p, 16, 64);
    p += __shfl_xor(p, 32, 64);
    if (kq == 0 && eok) out[sid] = p + b2f;
}

// ---- MFMA MLP over fully-src-sorted edges ----
__global__ __launch_bounds__(256, 2) void edge_mlp_mfma_kernel(
    const __half* __restrict__ hh,
    const __half* __restrict__ w1t,    // [32][128] fp16
    const int2*  __restrict__ spair,   // sorted (src,dst)
    const int*   __restrict__ seid,    // sorted -> original edge id
    const float* __restrict__ b1,
    const float* __restrict__ W2,
    const float* __restrict__ b2,
    float*       __restrict__ out,
    int n_edges, int nblocks)
{
    // Bijective XCD chunking: contiguous sorted range per XCD -> src rows L2-hit.
    int bid = blockIdx.x;
    int q8 = nblocks >> 3, r8 = nblocks & 7;
    int xcd = bid & 7, idx = bid >> 3;
    int chunk = (xcd < r8) ? (xcd * (q8 + 1) + idx)
                           : (r8 * (q8 + 1) + (xcd - r8) * q8 + idx);
    int tile = chunk * 256;

    int lane = (int)(threadIdx.x & 63);
    int wv   = (int)(threadIdx.x >> 6);
    int m    = lane & 15;
    int kq   = lane >> 4;
    int koff = kq * 8;

    // A fragments: w1frag[nt][s] = W1T rows (hidden) 16*nt+m, k = 32*s+kq*8+[0..8)
    f16x8 w1frag[2][4];
#pragma unroll
    for (int nt = 0; nt < 2; ++nt)
#pragma unroll
        for (int s = 0; s < 4; ++s) {
            U16 t;
            t.u = *reinterpret_cast<const uint4*>(
                w1t + (size_t)(nt * 16 + m) * H_FEATS + s * 32 + koff);
            w1frag[nt][s] = t.h;
        }

    // Per-lane bias/W2 slices: hidden j = kq*4+r (acc0) and 16+kq*4+r (acc1).
    float4 b1lo = *reinterpret_cast<const float4*>(b1 + kq * 4);
    float4 b1hi = *reinterpret_cast<const float4*>(b1 + 16 + kq * 4);
    float4 w2lo = *reinterpret_cast<const float4*>(W2 + kq * 4);
    float4 w2hi = *reinterpret_cast<const float4*>(W2 + 16 + kq * 4);
    const float* b1lop = reinterpret_cast<const float*>(&b1lo);
    const float* b1hip = reinterpret_cast<const float*>(&b1hi);
    const float* w2lop = reinterpret_cast<const float*>(&w2lo);
    const float* w2hip = reinterpret_cast<const float*>(&w2hi);
    float b2f = b2[0];

    int base = tile + wv * 64;

    // Preload edge metadata for all 4 groups.
    int e0 = base + m,      e1 = base + 16 + m;
    int e2 = base + 32 + m, e3 = base + 48 + m;
    bool ok0 = e0 < n_edges, ok1 = e1 < n_edges, ok2 = e2 < n_edges, ok3 = e3 < n_edges;
    int2 sp0 = spair[ok0 ? e0 : n_edges - 1];
    int2 sp1 = spair[ok1 ? e1 : n_edges - 1];
    int2 sp2 = spair[ok2 ? e2 : n_edges - 1];
    int2 sp3 = spair[ok3 ? e3 : n_edges - 1];
    int sid0 = seid[ok0 ? e0 : n_edges - 1];
    int sid1 = seid[ok1 ? e1 : n_edges - 1];
    int sid2 = seid[ok2 ? e2 : n_edges - 1];
    int sid3 = seid[ok3 ? e3 : n_edges - 1];

    // Three named buffer sets (24 uint4 = 96 VGPRs of gather data in flight).
    U16 xA[4], xB[4];
    U16 yA[4], yB[4];
    U16 zA[4], zB[4];

    issue_g(hh, sp0, koff, xA, xB);
    issue_g(hh, sp1, koff, yA, yB);
    issue_g(hh, sp2, koff, zA, zB);
    __builtin_amdgcn_sched_barrier(0);
    compute_g(xA, xB, w1frag, b1lop, b1hip, w2lop, w2hip, b2f, kq, sid0, ok0, out);
    __builtin_amdgcn_sched_barrier(0);
    issue_g(hh, sp3, koff, xA, xB);
    __builtin_amdgcn_sched_barrier(0);
    compute_g(yA, yB, w1frag, b1lop, b1hip, w2lop, w2hip, b2f, kq, sid1, ok1, out);
    __builtin_amdgcn_sched_barrier(0);
    compute_g(zA, zB, w1frag, b1lop, b1hip, w2lop, w2hip, b2f, kq, sid2, ok2, out);
    __builtin_amdgcn_sched_barrier(0);
    compute_g(xA, xB, w1frag, b1lop, b1hip, w2lop, w2hip, b2f, kq, sid3, ok3, out);
}

// ---- Fallback: unsorted fp16 scalar path ----
__global__ __launch_bounds__(256) void edge_mlp_fp16_kernel(
    const __half* __restrict__ hh,
    const int*   __restrict__ src,
    const int*   __restrict__ dst,
    const float* __restrict__ W1,
    const float* __restrict__ b1,
    const float* __restrict__ W2,
    const float* __restrict__ b2,
    float*       __restrict__ out,
    int n_edges)
{
    int e = blockIdx.x * blockDim.x + threadIdx.x;
    if (e >= n_edges) return;

    const __half* hs = hh + (size_t)src[e] * H_FEATS;
    const __half* hd = hh + (size_t)dst[e] * H_FEATS;

    float hidden[HIDDEN];
#pragma unroll
    for (int j = 0; j < HIDDEN; ++j) hidden[j] = b1[j];

#pragma unroll 2
    for (int f0 = 0; f0 < H_FEATS; f0 += 8) {
        H8 A, B;
        A.u = *reinterpret_cast<const uint4*>(hs + f0);
        B.u = *reinterpret_cast<const uint4*>(hd + f0);
        float he[8];
#pragma unroll
        for (int k = 0; k < 4; ++k) {
            float2 a = __half22float2(A.h2[k]);
            float2 b = __half22float2(B.h2[k]);
            he[2 * k]     = a.x * b.x;
            he[2 * k + 1] = a.y * b.y;
        }
        const float* w = W1 + (size_t)f0 * HIDDEN;
#pragma unroll
        for (int j = 0; j < HIDDEN; ++j) {
            float acc = hidden[j];
#pragma unroll
            for (int k = 0; k < 8; ++k)
                acc = fmaf(he[k], w[(size_t)k * HIDDEN + j], acc);
            hidden[j] = acc;
        }
    }

    float score = b2[0];
#pragma unroll
    for (int j = 0; j < HIDDEN; ++j) {
        float r = hidden[j] > 0.0f ? hidden[j] : 0.0f;
        score = fmaf(r, W2[j], score);
    }
    out[e] = score;
}

// ---- Fallback: fp32 path (tiny ws) ----
__global__ __launch_bounds__(256) void edge_mlp_kernel(
    const float* __restrict__ h,
    const int*   __restrict__ src,
    const int*   __restrict__ dst,
    const float* __restrict__ W1,
    const float* __restrict__ b1,
    const float* __restrict__ W2,
    const float* __restrict__ b2,
    float*       __restrict__ out,
    int n_edges)
{
    int e = blockIdx.x * blockDim.x + threadIdx.x;
    if (e >= n_edges) return;

    const float* hs = h + (size_t)src[e] * H_FEATS;
    const float* hd = h + (size_t)dst[e] * H_FEATS;

    float hidden[HIDDEN];
#pragma unroll
    for (int j = 0; j < HIDDEN; ++j) hidden[j] = b1[j];

#pragma unroll 4
    for (int f0 = 0; f0 < H_FEATS; f0 += 4) {
        float4 a = *reinterpret_cast<const float4*>(hs + f0);
        float4 b = *reinterpret_cast<const float4*>(hd + f0);
        float he0 = a.x * b.x, he1 = a.y * b.y, he2 = a.z * b.z, he3 = a.w * b.w;
        const float* w0 = W1 + (size_t)(f0 + 0) * HIDDEN;
        const float* w1 = W1 + (size_t)(f0 + 1) * HIDDEN;
        const float* w2 = W1 + (size_t)(f0 + 2) * HIDDEN;
        const float* w3 = W1 + (size_t)(f0 + 3) * HIDDEN;
#pragma unroll
        for (int j = 0; j < HIDDEN; ++j) {
            float acc = hidden[j];
            acc = fmaf(he0, w0[j], acc);
            acc = fmaf(he1, w1[j], acc);
            acc = fmaf(he2, w2[j], acc);
            acc = fmaf(he3, w3[j], acc);
            hidden[j] = acc;
        }
    }

    float score = b2[0];
#pragma unroll
    for (int j = 0; j < HIDDEN; ++j) {
        float r = hidden[j] > 0.0f ? hidden[j] : 0.0f;
        score = fmaf(r, W2[j], score);
    }
    out[e] = score;
}

extern "C" void kernel_launch(void* const* d_in, const int* in_sizes, int n_in,
                              void* d_out, int out_size, void* d_ws, size_t ws_size,
                              hipStream_t stream) {
    const float* h   = (const float*)d_in[0];
    const int*   src = (const int*)  d_in[1];
    const int*   dst = (const int*)  d_in[2];
    const float* W1  = (const float*)d_in[3];
    const float* b1  = (const float*)d_in[4];
    const float* W2  = (const float*)d_in[5];
    const float* b2  = (const float*)d_in[6];
    float* out = (float*)d_out;

    int n_node_feats = in_sizes[0];            // N * 128
    int n_edges = in_sizes[1];
    int n_nodes = n_node_feats / H_FEATS;
    int nbuck = (n_nodes + NB - 1) >> BUCKET_SHIFT;

    const int block = 256;
    int egrid  = (n_edges + block - 1) / block;          // MLP grid (256 edges/block)
    int sgrid  = (n_edges + SORT_EPB - 1) / SORT_EPB;    // sort-pass grid

    // ws layout (256B aligned)
    size_t hh_bytes   = (size_t)n_node_feats * sizeof(__half);
    size_t off_w1t    = (hh_bytes + 255) & ~(size_t)255;
    size_t off_spair  = (off_w1t + (size_t)H_FEATS * HIDDEN * 2 + 255) & ~(size_t)255;
    size_t off_seid   = off_spair + (size_t)n_edges * 8;
    size_t off_bh     = off_seid + (size_t)n_edges * 4;
    size_t off_rsum   = off_bh + (size_t)nbuck * sgrid * 4;
    size_t off_base   = off_rsum + (size_t)MAX_BUCKETS * 4;
    size_t need_1lvl  = off_base + (size_t)MAX_BUCKETS * 4;
    size_t off_spair2 = (need_1lvl + 255) & ~(size_t)255;
    size_t off_seid2  = off_spair2 + (size_t)n_edges * 8;
    size_t need_2lvl  = off_seid2 + (size_t)n_edges * 4;

    int n8 = n_node_feats / 8;

    if (ws_size >= need_1lvl && nbuck <= MAX_BUCKETS) {
        char* ws = (char*)d_ws;
        __half* hh     = (__half*)ws;
        __half* w1t    = (__half*)(ws + off_w1t);
        int2*   spair  = (int2*)(ws + off_spair);
        int*    seid   = (int*)(ws + off_seid);
        int*    blockhist = (int*)(ws + off_bh);
        int*    rowsum = (int*)(ws + off_rsum);
        int*    base   = (int*)(ws + off_base);

        int cb = (n8 + block - 1) / block;
        int wb = (H_FEATS * HIDDEN + block - 1) / block;
        int hb = sgrid;
        prep_fused_kernel<<<cb + wb + hb, block, 0, stream>>>(
            h, hh, n8, W1, w1t, src, blockhist, n_edges, nbuck, hb, cb, wb);
        scan_rows_kernel<<<nbuck, block, 0, stream>>>(blockhist, rowsum, sgrid);
        scan_base_kernel<<<1, MAX_BUCKETS, 0, stream>>>(rowsum, base, nbuck);
        scatter_kernel<<<sgrid, block, 0, stream>>>(src, dst, blockhist, base,
                                                    spair, seid,
                                                    n_edges, nbuck, sgrid);
        if (ws_size >= need_2lvl) {
            int2* spair2 = (int2*)(ws + off_spair2);
            int*  seid2  = (int*)(ws + off_seid2);
            subsort_kernel<<<nbuck, block, 0, stream>>>(spair, seid, base, rowsum,
                                                        spair2, seid2);
            edge_mlp_mfma_kernel<<<egrid, block, 0, stream>>>(hh, w1t, spair2, seid2,
                                                              b1, W2, b2, out,
                                                              n_edges, egrid);
        } else {
            edge_mlp_mfma_kernel<<<egrid, block, 0, stream>>>(hh, w1t, spair, seid,
                                                              b1, W2, b2, out,
                                                              n_edges, egrid);
        }
    } else if (ws_size >= hh_bytes) {
        __half* hh = (__half*)d_ws;
        convert_h_kernel<<<(n8 + block - 1) / block, block, 0, stream>>>(h, hh, n8);
        edge_mlp_fp16_kernel<<<egrid, block, 0, stream>>>(hh, src, dst,
                                                          W1, b1, W2, b2, out, n_edges);
    } else {
        edge_mlp_kernel<<<egrid, block, 0, stream>>>(h, src, dst,
                                                     W1, b1, W2, b2, out, n_edges);
    }
}

// Round 15
// 169.662 us; speedup vs baseline: 1.0870x; 1.0870x over previous
//
#include <hip/hip_runtime.h>
#include <hip/hip_bf16.h>
#include <hip/hip_fp16.h>

#define H_FEATS 128
#define HIDDEN  32
#define BUCKET_SHIFT 9            // 512 nodes/bucket: coalesced scatter (r14: finer
                                  // buckets fragment pass-C writes, +30us)
#define NB (1 << BUCKET_SHIFT)
#define MAX_BUCKETS 1024
#define SORT_EPB 4096             // edges per block in sort passes

typedef _Float16 f16x8 __attribute__((ext_vector_type(8)));
typedef float    f32x4 __attribute__((ext_vector_type(4)));

union H8 { uint4 u; __half2 h2[4]; };
union U16 { uint4 u; f16x8 h; };

// ---- device helpers for prep work ----
__device__ __forceinline__ void do_convert_h(
    const float* __restrict__ h, __half* __restrict__ hh, int i, int n8)
{
    if (i >= n8) return;
    const float4* s = reinterpret_cast<const float4*>(h) + (size_t)i * 2;
    float4 a = s[0], b = s[1];
    H8 r;
    r.h2[0] = __floats2half2_rn(a.x, a.y);
    r.h2[1] = __floats2half2_rn(a.z, a.w);
    r.h2[2] = __floats2half2_rn(b.x, b.y);
    r.h2[3] = __floats2half2_rn(b.z, b.w);
    reinterpret_cast<uint4*>(hh)[i] = r.u;
}

// ---- Fused prep: convert_h | convert_w | per-block histogram ----
__global__ __launch_bounds__(256) void prep_fused_kernel(
    const float* __restrict__ h, __half* __restrict__ hh, int n8,
    const float* __restrict__ W1, __half* __restrict__ w1t,
    const int* __restrict__ src, int* __restrict__ blockhist,
    int n_edges, int nbuck, int hb, int cb, int wb)
{
    __shared__ int lh[MAX_BUCKETS];
    int bid = blockIdx.x;
    int tid = threadIdx.x;

    if (bid < cb) {
        do_convert_h(h, hh, bid * 256 + tid, n8);
        return;
    }
    bid -= cb;
    if (bid < wb) {
        int t = bid * 256 + tid;
        if (t < H_FEATS * HIDDEN) {
            int k = t >> 5, n = t & 31;
            w1t[(size_t)n * H_FEATS + k] = __float2half(W1[t]);
        }
        return;
    }
    bid -= wb;
    // histogram block
    for (int i = tid; i < nbuck; i += 256) lh[i] = 0;
    __syncthreads();
    int ebase = bid * SORT_EPB;
#pragma unroll
    for (int k = 0; k < SORT_EPB / 256; ++k) {
        int e = ebase + k * 256 + tid;
        if (e < n_edges) atomicAdd(&lh[src[e] >> BUCKET_SHIFT], 1);  // LDS atomic
    }
    __syncthreads();
    for (int i = tid; i < nbuck; i += 256)
        blockhist[(size_t)i * hb + bid] = lh[i];
}

// ---- standalone convert (fallback paths) ----
__global__ __launch_bounds__(256) void convert_h_kernel(
    const float* __restrict__ h, __half* __restrict__ hh, int n8)
{
    do_convert_h(h, hh, blockIdx.x * blockDim.x + threadIdx.x, n8);
}

// ---- Sort pass B1: exclusive scan each bucket-row across blocks ----
__global__ __launch_bounds__(256) void scan_rows_kernel(
    int* __restrict__ blockhist, int* __restrict__ rowsum, int nblocks)
{
    __shared__ int tmp[256];
    int row = blockIdx.x;
    int tid = threadIdx.x;
    size_t rowbase = (size_t)row * nblocks;
    int carry = 0;
    for (int c = 0; c < nblocks; c += 256) {
        int idx = c + tid;
        int v = (idx < nblocks) ? blockhist[rowbase + idx] : 0;
        tmp[tid] = v;
        __syncthreads();
#pragma unroll
        for (int d = 1; d < 256; d <<= 1) {
            int t = (tid >= d) ? tmp[tid - d] : 0;
            __syncthreads();
            tmp[tid] += t;
            __syncthreads();
        }
        int incl = tmp[tid];
        if (idx < nblocks) blockhist[rowbase + idx] = carry + incl - v;
        carry += tmp[255];
        __syncthreads();
    }
    if (tid == 0) rowsum[row] = carry;
}

// ---- Sort pass B2: exclusive scan of bucket totals -> base ----
__global__ __launch_bounds__(MAX_BUCKETS) void scan_base_kernel(
    const int* __restrict__ rowsum, int* __restrict__ base, int nbuck)
{
    __shared__ int tmp[MAX_BUCKETS];
    int tid = threadIdx.x;
    int v = (tid < nbuck) ? rowsum[tid] : 0;
    tmp[tid] = v;
    __syncthreads();
#pragma unroll
    for (int d = 1; d < MAX_BUCKETS; d <<= 1) {
        int t = (tid >= d) ? tmp[tid - d] : 0;
        __syncthreads();
        tmp[tid] += t;
        __syncthreads();
    }
    if (tid < nbuck) base[tid] = tmp[tid] - v;
}

// ---- Sort pass C: place edges into bucket order (no global atomics) ----
__global__ __launch_bounds__(256) void scatter_kernel(
    const int* __restrict__ src, const int* __restrict__ dst,
    const int* __restrict__ blockhist, const int* __restrict__ base,
    int2* __restrict__ spair, int* __restrict__ seid,
    int n_edges, int nbuck, int nblocks)
{
    __shared__ int lcur[MAX_BUCKETS];
    int tid = threadIdx.x;
    for (int i = tid; i < nbuck; i += 256)
        lcur[i] = base[i] + blockhist[(size_t)i * nblocks + blockIdx.x];
    __syncthreads();
    int ebase = blockIdx.x * SORT_EPB;
#pragma unroll
    for (int k = 0; k < SORT_EPB / 256; ++k) {
        int e = ebase + k * 256 + tid;
        if (e < n_edges) {
            int s = src[e];
            int p = atomicAdd(&lcur[s >> BUCKET_SHIFT], 1);   // LDS atomic
            spair[p] = make_int2(s, dst[e]);
            seid[p] = e;
        }
    }
}

// ---- Sort pass D: per-bucket counting sort by low 9 bits -> full src order.
// 1024-thread blocks (r13's 256-thr version serialized: ~8200 edges/bucket,
// 196 blocks on 256 CUs, ~35us). 4x threads -> ~8 strided iterations.
// Full per-node sort makes consecutive edges share src (mean degree 16 ==
// MFMA group size): m-lanes gather ~1-2 distinct src rows, TA coalesces
// identical addresses (r13: MLP 127 -> 97.5us).
__global__ __launch_bounds__(1024) void subsort_kernel(
    const int2* __restrict__ spair1, const int* __restrict__ seid1,
    const int* __restrict__ base, const int* __restrict__ rowsum,
    int2* __restrict__ spair2, int* __restrict__ seid2)
{
    __shared__ int lh[NB];
    __shared__ int lcur[NB];
    __shared__ int tmp[1024];
    int b = blockIdx.x;
    int tid = threadIdx.x;
    int start = base[b];
    int cnt = rowsum[b];

    if (tid < NB) lh[tid] = 0;
    __syncthreads();
    for (int i = tid; i < cnt; i += 1024)
        atomicAdd(&lh[spair1[start + i].x & (NB - 1)], 1);
    __syncthreads();

    // exclusive scan of NB=512 entries; lanes >=NB carry zeros (harmless).
    int v = (tid < NB) ? lh[tid] : 0;
    tmp[tid] = v;
    __syncthreads();
#pragma unroll
    for (int d = 1; d < NB; d <<= 1) {
        int t = (tid >= d) ? tmp[tid - d] : 0;
        __syncthreads();
        tmp[tid] += t;
        __syncthreads();
    }
    if (tid < NB) lcur[tid] = tmp[tid] - v;
    __syncthreads();

    for (int i = tid; i < cnt; i += 1024) {
        int2 sp = spair1[start + i];
        int sid = seid1[start + i];
        int p = atomicAdd(&lcur[sp.x & (NB - 1)], 1);   // LDS atomic
        spair2[start + p] = sp;
        seid2[start + p] = sid;
    }
}

// ---- MFMA MLP helpers (arrays with compile-time indices only) ----
__device__ __forceinline__ void issue_g(
    const __half* __restrict__ hh, int2 sp, int koff, U16 (&A)[4], U16 (&B)[4])
{
    const __half* hs = hh + (size_t)sp.x * H_FEATS;
    const __half* hd = hh + (size_t)sp.y * H_FEATS;
#pragma unroll
    for (int s = 0; s < 4; ++s) {
        A[s].u = *reinterpret_cast<const uint4*>(hs + s * 32 + koff);
        B[s].u = *reinterpret_cast<const uint4*>(hd + s * 32 + koff);
    }
}

__device__ __forceinline__ void compute_g(
    U16 (&A)[4], U16 (&B)[4], const f16x8 (&w1frag)[2][4],
    const float* b1lop, const float* b1hip, const float* w2lop, const float* w2hip,
    float b2f, int kq, int sid, bool eok, float* __restrict__ out)
{
    f32x4 acc0 = {0.f, 0.f, 0.f, 0.f};
    f32x4 acc1 = {0.f, 0.f, 0.f, 0.f};
#pragma unroll
    for (int s = 0; s < 4; ++s) {
        f16x8 he = A[s].h * B[s].h;
        acc0 = __builtin_amdgcn_mfma_f32_16x16x32_f16(w1frag[0][s], he, acc0, 0, 0, 0);
        acc1 = __builtin_amdgcn_mfma_f32_16x16x32_f16(w1frag[1][s], he, acc1, 0, 0, 0);
    }
    float p = 0.f;
#pragma unroll
    for (int r = 0; r < 4; ++r) {
        float h0 = acc0[r] + b1lop[r]; h0 = h0 > 0.f ? h0 : 0.f;
        float h1 = acc1[r] + b1hip[r]; h1 = h1 > 0.f ? h1 : 0.f;
        p = fmaf(h0, w2lop[r], p);
        p = fmaf(h1, w2hip[r], p);
    }
    p += __shfl_xor(p, 16, 64);
    p += __shfl_xor(p, 32, 64);
    if (kq == 0 && eok) out[sid] = p + b2f;
}

// ---- MFMA MLP over fully-src-sorted edges ----
__global__ __launch_bounds__(256, 2) void edge_mlp_mfma_kernel(
    const __half* __restrict__ hh,
    const __half* __restrict__ w1t,    // [32][128] fp16
    const int2*  __restrict__ spair,   // sorted (src,dst)
    const int*   __restrict__ seid,    // sorted -> original edge id
    const float* __restrict__ b1,
    const float* __restrict__ W2,
    const float* __restrict__ b2,
    float*       __restrict__ out,
    int n_edges, int nblocks)
{
    // Bijective XCD chunking: contiguous sorted range per XCD -> src rows L2-hit.
    int bid = blockIdx.x;
    int q8 = nblocks >> 3, r8 = nblocks & 7;
    int xcd = bid & 7, idx = bid >> 3;
    int chunk = (xcd < r8) ? (xcd * (q8 + 1) + idx)
                           : (r8 * (q8 + 1) + (xcd - r8) * q8 + idx);
    int tile = chunk * 256;

    int lane = (int)(threadIdx.x & 63);
    int wv   = (int)(threadIdx.x >> 6);
    int m    = lane & 15;
    int kq   = lane >> 4;
    int koff = kq * 8;

    // A fragments: w1frag[nt][s] = W1T rows (hidden) 16*nt+m, k = 32*s+kq*8+[0..8)
    f16x8 w1frag[2][4];
#pragma unroll
    for (int nt = 0; nt < 2; ++nt)
#pragma unroll
        for (int s = 0; s < 4; ++s) {
            U16 t;
            t.u = *reinterpret_cast<const uint4*>(
                w1t + (size_t)(nt * 16 + m) * H_FEATS + s * 32 + koff);
            w1frag[nt][s] = t.h;
        }

    // Per-lane bias/W2 slices: hidden j = kq*4+r (acc0) and 16+kq*4+r (acc1).
    float4 b1lo = *reinterpret_cast<const float4*>(b1 + kq * 4);
    float4 b1hi = *reinterpret_cast<const float4*>(b1 + 16 + kq * 4);
    float4 w2lo = *reinterpret_cast<const float4*>(W2 + kq * 4);
    float4 w2hi = *reinterpret_cast<const float4*>(W2 + 16 + kq * 4);
    const float* b1lop = reinterpret_cast<const float*>(&b1lo);
    const float* b1hip = reinterpret_cast<const float*>(&b1hi);
    const float* w2lop = reinterpret_cast<const float*>(&w2lo);
    const float* w2hip = reinterpret_cast<const float*>(&w2hi);
    float b2f = b2[0];

    int base = tile + wv * 64;

    // Preload edge metadata for all 4 groups.
    int e0 = base + m,      e1 = base + 16 + m;
    int e2 = base + 32 + m, e3 = base + 48 + m;
    bool ok0 = e0 < n_edges, ok1 = e1 < n_edges, ok2 = e2 < n_edges, ok3 = e3 < n_edges;
    int2 sp0 = spair[ok0 ? e0 : n_edges - 1];
    int2 sp1 = spair[ok1 ? e1 : n_edges - 1];
    int2 sp2 = spair[ok2 ? e2 : n_edges - 1];
    int2 sp3 = spair[ok3 ? e3 : n_edges - 1];
    int sid0 = seid[ok0 ? e0 : n_edges - 1];
    int sid1 = seid[ok1 ? e1 : n_edges - 1];
    int sid2 = seid[ok2 ? e2 : n_edges - 1];
    int sid3 = seid[ok3 ? e3 : n_edges - 1];

    // Three named buffer sets (24 uint4 = 96 VGPRs of gather data in flight).
    U16 xA[4], xB[4];
    U16 yA[4], yB[4];
    U16 zA[4], zB[4];

    issue_g(hh, sp0, koff, xA, xB);
    issue_g(hh, sp1, koff, yA, yB);
    issue_g(hh, sp2, koff, zA, zB);
    __builtin_amdgcn_sched_barrier(0);
    compute_g(xA, xB, w1frag, b1lop, b1hip, w2lop, w2hip, b2f, kq, sid0, ok0, out);
    __builtin_amdgcn_sched_barrier(0);
    issue_g(hh, sp3, koff, xA, xB);
    __builtin_amdgcn_sched_barrier(0);
    compute_g(yA, yB, w1frag, b1lop, b1hip, w2lop, w2hip, b2f, kq, sid1, ok1, out);
    __builtin_amdgcn_sched_barrier(0);
    compute_g(zA, zB, w1frag, b1lop, b1hip, w2lop, w2hip, b2f, kq, sid2, ok2, out);
    __builtin_amdgcn_sched_barrier(0);
    compute_g(xA, xB, w1frag, b1lop, b1hip, w2lop, w2hip, b2f, kq, sid3, ok3, out);
}

// ---- Fallback: unsorted fp16 scalar path ----
__global__ __launch_bounds__(256) void edge_mlp_fp16_kernel(
    const __half* __restrict__ hh,
    const int*   __restrict__ src,
    const int*   __restrict__ dst,
    const float* __restrict__ W1,
    const float* __restrict__ b1,
    const float* __restrict__ W2,
    const float* __restrict__ b2,
    float*       __restrict__ out,
    int n_edges)
{
    int e = blockIdx.x * blockDim.x + threadIdx.x;
    if (e >= n_edges) return;

    const __half* hs = hh + (size_t)src[e] * H_FEATS;
    const __half* hd = hh + (size_t)dst[e] * H_FEATS;

    float hidden[HIDDEN];
#pragma unroll
    for (int j = 0; j < HIDDEN; ++j) hidden[j] = b1[j];

#pragma unroll 2
    for (int f0 = 0; f0 < H_FEATS; f0 += 8) {
        H8 A, B;
        A.u = *reinterpret_cast<const uint4*>(hs + f0);
        B.u = *reinterpret_cast<const uint4*>(hd + f0);
        float he[8];
#pragma unroll
        for (int k = 0; k < 4; ++k) {
            float2 a = __half22float2(A.h2[k]);
            float2 b = __half22float2(B.h2[k]);
            he[2 * k]     = a.x * b.x;
            he[2 * k + 1] = a.y * b.y;
        }
        const float* w = W1 + (size_t)f0 * HIDDEN;
#pragma unroll
        for (int j = 0; j < HIDDEN; ++j) {
            float acc = hidden[j];
#pragma unroll
            for (int k = 0; k < 8; ++k)
                acc = fmaf(he[k], w[(size_t)k * HIDDEN + j], acc);
            hidden[j] = acc;
        }
    }

    float score = b2[0];
#pragma unroll
    for (int j = 0; j < HIDDEN; ++j) {
        float r = hidden[j] > 0.0f ? hidden[j] : 0.0f;
        score = fmaf(r, W2[j], score);
    }
    out[e] = score;
}

// ---- Fallback: fp32 path (tiny ws) ----
__global__ __launch_bounds__(256) void edge_mlp_kernel(
    const float* __restrict__ h,
    const int*   __restrict__ src,
    const int*   __restrict__ dst,
    const float* __restrict__ W1,
    const float* __restrict__ b1,
    const float* __restrict__ W2,
    const float* __restrict__ b2,
    float*       __restrict__ out,
    int n_edges)
{
    int e = blockIdx.x * blockDim.x + threadIdx.x;
    if (e >= n_edges) return;

    const float* hs = h + (size_t)src[e] * H_FEATS;
    const float* hd = h + (size_t)dst[e] * H_FEATS;

    float hidden[HIDDEN];
#pragma unroll
    for (int j = 0; j < HIDDEN; ++j) hidden[j] = b1[j];

#pragma unroll 4
    for (int f0 = 0; f0 < H_FEATS; f0 += 4) {
        float4 a = *reinterpret_cast<const float4*>(hs + f0);
        float4 b = *reinterpret_cast<const float4*>(hd + f0);
        float he0 = a.x * b.x, he1 = a.y * b.y, he2 = a.z * b.z, he3 = a.w * b.w;
        const float* w0 = W1 + (size_t)(f0 + 0) * HIDDEN;
        const float* w1 = W1 + (size_t)(f0 + 1) * HIDDEN;
        const float* w2 = W1 + (size_t)(f0 + 2) * HIDDEN;
        const float* w3 = W1 + (size_t)(f0 + 3) * HIDDEN;
#pragma unroll
        for (int j = 0; j < HIDDEN; ++j) {
            float acc = hidden[j];
            acc = fmaf(he0, w0[j], acc);
            acc = fmaf(he1, w1[j], acc);
            acc = fmaf(he2, w2[j], acc);
            acc = fmaf(he3, w3[j], acc);
            hidden[j] = acc;
        }
    }

    float score = b2[0];
#pragma unroll
    for (int j = 0; j < HIDDEN; ++j) {
        float r = hidden[j] > 0.0f ? hidden[j] : 0.0f;
        score = fmaf(r, W2[j], score);
    }
    out[e] = score;
}

extern "C" void kernel_launch(void* const* d_in, const int* in_sizes, int n_in,
                              void* d_out, int out_size, void* d_ws, size_t ws_size,
                              hipStream_t stream) {
    const float* h   = (const float*)d_in[0];
    const int*   src = (const int*)  d_in[1];
    const int*   dst = (const int*)  d_in[2];
    const float* W1  = (const float*)d_in[3];
    const float* b1  = (const float*)d_in[4];
    const float* W2  = (const float*)d_in[5];
    const float* b2  = (const float*)d_in[6];
    float* out = (float*)d_out;

    int n_node_feats = in_sizes[0];            // N * 128
    int n_edges = in_sizes[1];
    int n_nodes = n_node_feats / H_FEATS;
    int nbuck = (n_nodes + NB - 1) >> BUCKET_SHIFT;

    const int block = 256;
    int egrid  = (n_edges + block - 1) / block;          // MLP grid (256 edges/block)
    int sgrid  = (n_edges + SORT_EPB - 1) / SORT_EPB;    // sort-pass grid

    // ws layout (256B aligned)
    size_t hh_bytes   = (size_t)n_node_feats * sizeof(__half);
    size_t off_w1t    = (hh_bytes + 255) & ~(size_t)255;
    size_t off_spair  = (off_w1t + (size_t)H_FEATS * HIDDEN * 2 + 255) & ~(size_t)255;
    size_t off_seid   = off_spair + (size_t)n_edges * 8;
    size_t off_bh     = off_seid + (size_t)n_edges * 4;
    size_t off_rsum   = off_bh + (size_t)nbuck * sgrid * 4;
    size_t off_base   = off_rsum + (size_t)MAX_BUCKETS * 4;
    size_t need_1lvl  = off_base + (size_t)MAX_BUCKETS * 4;
    size_t off_spair2 = (need_1lvl + 255) & ~(size_t)255;
    size_t off_seid2  = off_spair2 + (size_t)n_edges * 8;
    size_t need_2lvl  = off_seid2 + (size_t)n_edges * 4;

    int n8 = n_node_feats / 8;

    if (ws_size >= need_1lvl && nbuck <= MAX_BUCKETS) {
        char* ws = (char*)d_ws;
        __half* hh     = (__half*)ws;
        __half* w1t    = (__half*)(ws + off_w1t);
        int2*   spair  = (int2*)(ws + off_spair);
        int*    seid   = (int*)(ws + off_seid);
        int*    blockhist = (int*)(ws + off_bh);
        int*    rowsum = (int*)(ws + off_rsum);
        int*    base   = (int*)(ws + off_base);

        int cb = (n8 + block - 1) / block;
        int wb = (H_FEATS * HIDDEN + block - 1) / block;
        int hb = sgrid;
        prep_fused_kernel<<<cb + wb + hb, block, 0, stream>>>(
            h, hh, n8, W1, w1t, src, blockhist, n_edges, nbuck, hb, cb, wb);
        scan_rows_kernel<<<nbuck, block, 0, stream>>>(blockhist, rowsum, sgrid);
        scan_base_kernel<<<1, MAX_BUCKETS, 0, stream>>>(rowsum, base, nbuck);
        scatter_kernel<<<sgrid, block, 0, stream>>>(src, dst, blockhist, base,
                                                    spair, seid,
                                                    n_edges, nbuck, sgrid);
        if (ws_size >= need_2lvl) {
            int2* spair2 = (int2*)(ws + off_spair2);
            int*  seid2  = (int*)(ws + off_seid2);
            subsort_kernel<<<nbuck, 1024, 0, stream>>>(spair, seid, base, rowsum,
                                                       spair2, seid2);
            edge_mlp_mfma_kernel<<<egrid, block, 0, stream>>>(hh, w1t, spair2, seid2,
                                                              b1, W2, b2, out,
                                                              n_edges, egrid);
        } else {
            edge_mlp_mfma_kernel<<<egrid, block, 0, stream>>>(hh, w1t, spair, seid,
                                                              b1, W2, b2, out,
                                                              n_edges, egrid);
        }
    } else if (ws_size >= hh_bytes) {
        __half* hh = (__half*)d_ws;
        convert_h_kernel<<<(n8 + block - 1) / block, block, 0, stream>>>(h, hh, n8);
        edge_mlp_fp16_kernel<<<egrid, block, 0, stream>>>(hh, src, dst,
                                                          W1, b1, W2, b2, out, n_edges);
    } else {
        edge_mlp_kernel<<<egrid, block, 0, stream>>>(h, src, dst,
                                                     W1, b1, W2, b2, out, n_edges);
    }
}

// Round 16
// 151.725 us; speedup vs baseline: 1.2155x; 1.1182x over previous
//
#include <hip/hip_runtime.h>
#include <hip/hip_bf16.h>
#include <hip/hip_fp16.h>

#define H_FEATS 128
#define HIDDEN  32
#define BUCKET_SHIFT 9            // 512 nodes/bucket: coalesced scatter
#define NB (1 << BUCKET_SHIFT)
#define MAX_BUCKETS 1024
#define SORT_EPB 4096             // edges per block in sort passes

// Packed edge record: src[63:47] | dst[46:30] | eid[20:0]
// (valid while n_nodes < 2^17 and n_edges < 2^21; guarded in kernel_launch)
#define PACK_E(s, d, e) (((unsigned long long)(s) << 47) | \
                         ((unsigned long long)(d) << 30) | (unsigned long long)(e))
#define UNPACK_SRC(v) ((int)((v) >> 47))
#define UNPACK_DST(v) ((int)(((v) >> 30) & 0x1FFFF))
#define UNPACK_EID(v) ((int)((v) & 0x1FFFFF))

typedef _Float16 f16x8 __attribute__((ext_vector_type(8)));
typedef float    f32x4 __attribute__((ext_vector_type(4)));

union H8 { uint4 u; __half2 h2[4]; };
union U16 { uint4 u; f16x8 h; };

// ---- device helpers for prep work ----
__device__ __forceinline__ void do_convert_h(
    const float* __restrict__ h, __half* __restrict__ hh, int i, int n8)
{
    if (i >= n8) return;
    const float4* s = reinterpret_cast<const float4*>(h) + (size_t)i * 2;
    float4 a = s[0], b = s[1];
    H8 r;
    r.h2[0] = __floats2half2_rn(a.x, a.y);
    r.h2[1] = __floats2half2_rn(a.z, a.w);
    r.h2[2] = __floats2half2_rn(b.x, b.y);
    r.h2[3] = __floats2half2_rn(b.z, b.w);
    reinterpret_cast<uint4*>(hh)[i] = r.u;
}

// ---- Fused prep: convert_h | convert_w | per-block histogram ----
__global__ __launch_bounds__(256) void prep_fused_kernel(
    const float* __restrict__ h, __half* __restrict__ hh, int n8,
    const float* __restrict__ W1, __half* __restrict__ w1t,
    const int* __restrict__ src, int* __restrict__ blockhist,
    int n_edges, int nbuck, int hb, int cb, int wb)
{
    __shared__ int lh[MAX_BUCKETS];
    int bid = blockIdx.x;
    int tid = threadIdx.x;

    if (bid < cb) {
        do_convert_h(h, hh, bid * 256 + tid, n8);
        return;
    }
    bid -= cb;
    if (bid < wb) {
        int t = bid * 256 + tid;
        if (t < H_FEATS * HIDDEN) {
            int k = t >> 5, n = t & 31;
            w1t[(size_t)n * H_FEATS + k] = __float2half(W1[t]);
        }
        return;
    }
    bid -= wb;
    // histogram block
    for (int i = tid; i < nbuck; i += 256) lh[i] = 0;
    __syncthreads();
    int ebase = bid * SORT_EPB;
#pragma unroll
    for (int k = 0; k < SORT_EPB / 256; ++k) {
        int e = ebase + k * 256 + tid;
        if (e < n_edges) atomicAdd(&lh[src[e] >> BUCKET_SHIFT], 1);  // LDS atomic
    }
    __syncthreads();
    for (int i = tid; i < nbuck; i += 256)
        blockhist[(size_t)i * hb + bid] = lh[i];
}

// ---- standalone convert (fallback paths) ----
__global__ __launch_bounds__(256) void convert_h_kernel(
    const float* __restrict__ h, __half* __restrict__ hh, int n8)
{
    do_convert_h(h, hh, blockIdx.x * blockDim.x + threadIdx.x, n8);
}

// ---- Sort pass B1: exclusive scan each bucket-row across blocks ----
__global__ __launch_bounds__(256) void scan_rows_kernel(
    int* __restrict__ blockhist, int* __restrict__ rowsum, int nblocks)
{
    __shared__ int tmp[256];
    int row = blockIdx.x;
    int tid = threadIdx.x;
    size_t rowbase = (size_t)row * nblocks;
    int carry = 0;
    for (int c = 0; c < nblocks; c += 256) {
        int idx = c + tid;
        int v = (idx < nblocks) ? blockhist[rowbase + idx] : 0;
        tmp[tid] = v;
        __syncthreads();
#pragma unroll
        for (int d = 1; d < 256; d <<= 1) {
            int t = (tid >= d) ? tmp[tid - d] : 0;
            __syncthreads();
            tmp[tid] += t;
            __syncthreads();
        }
        int incl = tmp[tid];
        if (idx < nblocks) blockhist[rowbase + idx] = carry + incl - v;
        carry += tmp[255];
        __syncthreads();
    }
    if (tid == 0) rowsum[row] = carry;
}

// ---- Sort pass B2: exclusive scan of bucket totals -> base ----
__global__ __launch_bounds__(MAX_BUCKETS) void scan_base_kernel(
    const int* __restrict__ rowsum, int* __restrict__ base, int nbuck)
{
    __shared__ int tmp[MAX_BUCKETS];
    int tid = threadIdx.x;
    int v = (tid < nbuck) ? rowsum[tid] : 0;
    tmp[tid] = v;
    __syncthreads();
#pragma unroll
    for (int d = 1; d < MAX_BUCKETS; d <<= 1) {
        int t = (tid >= d) ? tmp[tid - d] : 0;
        __syncthreads();
        tmp[tid] += t;
        __syncthreads();
    }
    if (tid < nbuck) base[tid] = tmp[tid] - v;
}

// ---- Sort pass C: place packed edges into bucket order ----
__global__ __launch_bounds__(256) void scatter_kernel(
    const int* __restrict__ src, const int* __restrict__ dst,
    const int* __restrict__ blockhist, const int* __restrict__ base,
    unsigned long long* __restrict__ epack, int n_edges, int nbuck, int nblocks)
{
    __shared__ int lcur[MAX_BUCKETS];
    int tid = threadIdx.x;
    for (int i = tid; i < nbuck; i += 256)
        lcur[i] = base[i] + blockhist[(size_t)i * nblocks + blockIdx.x];
    __syncthreads();
    int ebase = blockIdx.x * SORT_EPB;
#pragma unroll
    for (int k = 0; k < SORT_EPB / 256; ++k) {
        int e = ebase + k * 256 + tid;
        if (e < n_edges) {
            int s = src[e];
            int p = atomicAdd(&lcur[s >> BUCKET_SHIFT], 1);   // LDS atomic
            epack[p] = PACK_E(s, dst[e], e);
        }
    }
}

// ---- Sort pass D: per-bucket counting sort by low 9 bits of src ----
// 1024-thread blocks (r15: 176->169.7us total). Full per-node sort makes
// consecutive edges share src (mean degree 16 == MFMA group size): m-lanes
// gather ~1-2 distinct rows; TA coalesces (r13: MLP 127 -> 97.5us).
__global__ __launch_bounds__(1024) void subsort_kernel(
    const unsigned long long* __restrict__ epack1,
    const int* __restrict__ base, const int* __restrict__ rowsum,
    unsigned long long* __restrict__ epack2)
{
    __shared__ int lh[NB];
    __shared__ int lcur[NB];
    __shared__ int tmp[1024];
    int b = blockIdx.x;
    int tid = threadIdx.x;
    int start = base[b];
    int cnt = rowsum[b];

    if (tid < NB) lh[tid] = 0;
    __syncthreads();
    for (int i = tid; i < cnt; i += 1024)
        atomicAdd(&lh[(int)((epack1[start + i] >> 47) & (NB - 1))], 1);
    __syncthreads();

    int v = (tid < NB) ? lh[tid] : 0;
    tmp[tid] = v;
    __syncthreads();
#pragma unroll
    for (int d = 1; d < NB; d <<= 1) {
        int t = (tid >= d) ? tmp[tid - d] : 0;
        __syncthreads();
        tmp[tid] += t;
        __syncthreads();
    }
    if (tid < NB) lcur[tid] = tmp[tid] - v;
    __syncthreads();

    for (int i = tid; i < cnt; i += 1024) {
        unsigned long long ep = epack1[start + i];
        int p = atomicAdd(&lcur[(int)((ep >> 47) & (NB - 1))], 1);  // LDS atomic
        epack2[start + p] = ep;
    }
}

// ---- MFMA MLP helpers (arrays with compile-time indices only) ----
__device__ __forceinline__ void issue_g(
    const __half* __restrict__ hh, unsigned long long ep, int koff,
    U16 (&A)[4], U16 (&B)[4])
{
    const __half* hs = hh + (size_t)UNPACK_SRC(ep) * H_FEATS;
    const __half* hd = hh + (size_t)UNPACK_DST(ep) * H_FEATS;
#pragma unroll
    for (int s = 0; s < 4; ++s) {
        A[s].u = *reinterpret_cast<const uint4*>(hs + s * 32 + koff);
        B[s].u = *reinterpret_cast<const uint4*>(hd + s * 32 + koff);
    }
}

__device__ __forceinline__ void compute_g(
    U16 (&A)[4], U16 (&B)[4], const f16x8 (&w1frag)[2][4],
    const float* b1lop, const float* b1hip, const float* w2lop, const float* w2hip,
    float b2f, int kq, int sid, bool eok, float* __restrict__ out)
{
    f32x4 acc0 = {0.f, 0.f, 0.f, 0.f};
    f32x4 acc1 = {0.f, 0.f, 0.f, 0.f};
#pragma unroll
    for (int s = 0; s < 4; ++s) {
        f16x8 he = A[s].h * B[s].h;
        acc0 = __builtin_amdgcn_mfma_f32_16x16x32_f16(w1frag[0][s], he, acc0, 0, 0, 0);
        acc1 = __builtin_amdgcn_mfma_f32_16x16x32_f16(w1frag[1][s], he, acc1, 0, 0, 0);
    }
    float p = 0.f;
#pragma unroll
    for (int r = 0; r < 4; ++r) {
        float h0 = acc0[r] + b1lop[r]; h0 = h0 > 0.f ? h0 : 0.f;
        float h1 = acc1[r] + b1hip[r]; h1 = h1 > 0.f ? h1 : 0.f;
        p = fmaf(h0, w2lop[r], p);
        p = fmaf(h1, w2hip[r], p);
    }
    p += __shfl_xor(p, 16, 64);
    p += __shfl_xor(p, 32, 64);
    if (kq == 0 && eok) out[sid] = p + b2f;
}

// ---- MFMA MLP over fully-src-sorted packed edges ----
__global__ __launch_bounds__(256, 2) void edge_mlp_mfma_kernel(
    const __half* __restrict__ hh,
    const __half* __restrict__ w1t,    // [32][128] fp16
    const unsigned long long* __restrict__ epack,   // sorted packed edges
    const float* __restrict__ b1,
    const float* __restrict__ W2,
    const float* __restrict__ b2,
    float*       __restrict__ out,
    int n_edges, int nblocks)
{
    // Bijective XCD chunking: contiguous sorted range per XCD -> src rows L2-hit.
    int bid = blockIdx.x;
    int q8 = nblocks >> 3, r8 = nblocks & 7;
    int xcd = bid & 7, idx = bid >> 3;
    int chunk = (xcd < r8) ? (xcd * (q8 + 1) + idx)
                           : (r8 * (q8 + 1) + (xcd - r8) * q8 + idx);
    int tile = chunk * 256;

    int lane = (int)(threadIdx.x & 63);
    int wv   = (int)(threadIdx.x >> 6);
    int m    = lane & 15;
    int kq   = lane >> 4;
    int koff = kq * 8;

    // A fragments: w1frag[nt][s] = W1T rows (hidden) 16*nt+m, k = 32*s+kq*8+[0..8)
    f16x8 w1frag[2][4];
#pragma unroll
    for (int nt = 0; nt < 2; ++nt)
#pragma unroll
        for (int s = 0; s < 4; ++s) {
            U16 t;
            t.u = *reinterpret_cast<const uint4*>(
                w1t + (size_t)(nt * 16 + m) * H_FEATS + s * 32 + koff);
            w1frag[nt][s] = t.h;
        }

    // Per-lane bias/W2 slices: hidden j = kq*4+r (acc0) and 16+kq*4+r (acc1).
    float4 b1lo = *reinterpret_cast<const float4*>(b1 + kq * 4);
    float4 b1hi = *reinterpret_cast<const float4*>(b1 + 16 + kq * 4);
    float4 w2lo = *reinterpret_cast<const float4*>(W2 + kq * 4);
    float4 w2hi = *reinterpret_cast<const float4*>(W2 + 16 + kq * 4);
    const float* b1lop = reinterpret_cast<const float*>(&b1lo);
    const float* b1hip = reinterpret_cast<const float*>(&b1hi);
    const float* w2lop = reinterpret_cast<const float*>(&w2lo);
    const float* w2hip = reinterpret_cast<const float*>(&w2hi);
    float b2f = b2[0];

    int base = tile + wv * 64;

    // Preload packed edge metadata for all 4 groups (one 8B load each).
    int e0 = base + m,      e1 = base + 16 + m;
    int e2 = base + 32 + m, e3 = base + 48 + m;
    bool ok0 = e0 < n_edges, ok1 = e1 < n_edges, ok2 = e2 < n_edges, ok3 = e3 < n_edges;
    unsigned long long ep0 = epack[ok0 ? e0 : n_edges - 1];
    unsigned long long ep1 = epack[ok1 ? e1 : n_edges - 1];
    unsigned long long ep2 = epack[ok2 ? e2 : n_edges - 1];
    unsigned long long ep3 = epack[ok3 ? e3 : n_edges - 1];
    int sid0 = UNPACK_EID(ep0), sid1 = UNPACK_EID(ep1);
    int sid2 = UNPACK_EID(ep2), sid3 = UNPACK_EID(ep3);

    // Three named buffer sets (24 uint4 = 96 VGPRs of gather data in flight).
    U16 xA[4], xB[4];
    U16 yA[4], yB[4];
    U16 zA[4], zB[4];

    issue_g(hh, ep0, koff, xA, xB);
    issue_g(hh, ep1, koff, yA, yB);
    issue_g(hh, ep2, koff, zA, zB);
    __builtin_amdgcn_sched_barrier(0);
    compute_g(xA, xB, w1frag, b1lop, b1hip, w2lop, w2hip, b2f, kq, sid0, ok0, out);
    __builtin_amdgcn_sched_barrier(0);
    issue_g(hh, ep3, koff, xA, xB);
    __builtin_amdgcn_sched_barrier(0);
    compute_g(yA, yB, w1frag, b1lop, b1hip, w2lop, w2hip, b2f, kq, sid1, ok1, out);
    __builtin_amdgcn_sched_barrier(0);
    compute_g(zA, zB, w1frag, b1lop, b1hip, w2lop, w2hip, b2f, kq, sid2, ok2, out);
    __builtin_amdgcn_sched_barrier(0);
    compute_g(xA, xB, w1frag, b1lop, b1hip, w2lop, w2hip, b2f, kq, sid3, ok3, out);
}

// ---- Fallback: unsorted fp16 scalar path ----
__global__ __launch_bounds__(256) void edge_mlp_fp16_kernel(
    const __half* __restrict__ hh,
    const int*   __restrict__ src,
    const int*   __restrict__ dst,
    const float* __restrict__ W1,
    const float* __restrict__ b1,
    const float* __restrict__ W2,
    const float* __restrict__ b2,
    float*       __restrict__ out,
    int n_edges)
{
    int e = blockIdx.x * blockDim.x + threadIdx.x;
    if (e >= n_edges) return;

    const __half* hs = hh + (size_t)src[e] * H_FEATS;
    const __half* hd = hh + (size_t)dst[e] * H_FEATS;

    float hidden[HIDDEN];
#pragma unroll
    for (int j = 0; j < HIDDEN; ++j) hidden[j] = b1[j];

#pragma unroll 2
    for (int f0 = 0; f0 < H_FEATS; f0 += 8) {
        H8 A, B;
        A.u = *reinterpret_cast<const uint4*>(hs + f0);
        B.u = *reinterpret_cast<const uint4*>(hd + f0);
        float he[8];
#pragma unroll
        for (int k = 0; k < 4; ++k) {
            float2 a = __half22float2(A.h2[k]);
            float2 b = __half22float2(B.h2[k]);
            he[2 * k]     = a.x * b.x;
            he[2 * k + 1] = a.y * b.y;
        }
        const float* w = W1 + (size_t)f0 * HIDDEN;
#pragma unroll
        for (int j = 0; j < HIDDEN; ++j) {
            float acc = hidden[j];
#pragma unroll
            for (int k = 0; k < 8; ++k)
                acc = fmaf(he[k], w[(size_t)k * HIDDEN + j], acc);
            hidden[j] = acc;
        }
    }

    float score = b2[0];
#pragma unroll
    for (int j = 0; j < HIDDEN; ++j) {
        float r = hidden[j] > 0.0f ? hidden[j] : 0.0f;
        score = fmaf(r, W2[j], score);
    }
    out[e] = score;
}

// ---- Fallback: fp32 path (tiny ws) ----
__global__ __launch_bounds__(256) void edge_mlp_kernel(
    const float* __restrict__ h,
    const int*   __restrict__ src,
    const int*   __restrict__ dst,
    const float* __restrict__ W1,
    const float* __restrict__ b1,
    const float* __restrict__ W2,
    const float* __restrict__ b2,
    float*       __restrict__ out,
    int n_edges)
{
    int e = blockIdx.x * blockDim.x + threadIdx.x;
    if (e >= n_edges) return;

    const float* hs = h + (size_t)src[e] * H_FEATS;
    const float* hd = h + (size_t)dst[e] * H_FEATS;

    float hidden[HIDDEN];
#pragma unroll
    for (int j = 0; j < HIDDEN; ++j) hidden[j] = b1[j];

#pragma unroll 4
    for (int f0 = 0; f0 < H_FEATS; f0 += 4) {
        float4 a = *reinterpret_cast<const float4*>(hs + f0);
        float4 b = *reinterpret_cast<const float4*>(hd + f0);
        float he0 = a.x * b.x, he1 = a.y * b.y, he2 = a.z * b.z, he3 = a.w * b.w;
        const float* w0 = W1 + (size_t)(f0 + 0) * HIDDEN;
        const float* w1 = W1 + (size_t)(f0 + 1) * HIDDEN;
        const float* w2 = W1 + (size_t)(f0 + 2) * HIDDEN;
        const float* w3 = W1 + (size_t)(f0 + 3) * HIDDEN;
#pragma unroll
        for (int j = 0; j < HIDDEN; ++j) {
            float acc = hidden[j];
            acc = fmaf(he0, w0[j], acc);
            acc = fmaf(he1, w1[j], acc);
            acc = fmaf(he2, w2[j], acc);
            acc = fmaf(he3, w3[j], acc);
            hidden[j] = acc;
        }
    }

    float score = b2[0];
#pragma unroll
    for (int j = 0; j < HIDDEN; ++j) {
        float r = hidden[j] > 0.0f ? hidden[j] : 0.0f;
        score = fmaf(r, W2[j], score);
    }
    out[e] = score;
}

extern "C" void kernel_launch(void* const* d_in, const int* in_sizes, int n_in,
                              void* d_out, int out_size, void* d_ws, size_t ws_size,
                              hipStream_t stream) {
    const float* h   = (const float*)d_in[0];
    const int*   src = (const int*)  d_in[1];
    const int*   dst = (const int*)  d_in[2];
    const float* W1  = (const float*)d_in[3];
    const float* b1  = (const float*)d_in[4];
    const float* W2  = (const float*)d_in[5];
    const float* b2  = (const float*)d_in[6];
    float* out = (float*)d_out;

    int n_node_feats = in_sizes[0];            // N * 128
    int n_edges = in_sizes[1];
    int n_nodes = n_node_feats / H_FEATS;
    int nbuck = (n_nodes + NB - 1) >> BUCKET_SHIFT;

    const int block = 256;
    int egrid  = (n_edges + block - 1) / block;          // MLP grid (256 edges/block)
    int sgrid  = (n_edges + SORT_EPB - 1) / SORT_EPB;    // sort-pass grid

    // ws layout (256B aligned)
    size_t hh_bytes   = (size_t)n_node_feats * sizeof(__half);
    size_t off_w1t    = (hh_bytes + 255) & ~(size_t)255;
    size_t off_ep1    = (off_w1t + (size_t)H_FEATS * HIDDEN * 2 + 255) & ~(size_t)255;
    size_t off_bh     = off_ep1 + (size_t)n_edges * 8;
    size_t off_rsum   = off_bh + (size_t)nbuck * sgrid * 4;
    size_t off_base   = off_rsum + (size_t)MAX_BUCKETS * 4;
    size_t off_ep2    = ((off_base + (size_t)MAX_BUCKETS * 4) + 255) & ~(size_t)255;
    size_t need_full  = off_ep2 + (size_t)n_edges * 8;

    int n8 = n_node_feats / 8;
    bool pack_ok = (n_nodes < (1 << 17)) && (n_edges < (1 << 21));

    if (ws_size >= need_full && nbuck <= MAX_BUCKETS && pack_ok) {
        char* ws = (char*)d_ws;
        __half* hh     = (__half*)ws;
        __half* w1t    = (__half*)(ws + off_w1t);
        unsigned long long* ep1 = (unsigned long long*)(ws + off_ep1);
        int*    blockhist = (int*)(ws + off_bh);
        int*    rowsum = (int*)(ws + off_rsum);
        int*    base   = (int*)(ws + off_base);
        unsigned long long* ep2 = (unsigned long long*)(ws + off_ep2);

        int cb = (n8 + block - 1) / block;
        int wb = (H_FEATS * HIDDEN + block - 1) / block;
        int hb = sgrid;
        prep_fused_kernel<<<cb + wb + hb, block, 0, stream>>>(
            h, hh, n8, W1, w1t, src, blockhist, n_edges, nbuck, hb, cb, wb);
        scan_rows_kernel<<<nbuck, block, 0, stream>>>(blockhist, rowsum, sgrid);
        scan_base_kernel<<<1, MAX_BUCKETS, 0, stream>>>(rowsum, base, nbuck);
        scatter_kernel<<<sgrid, block, 0, stream>>>(src, dst, blockhist, base,
                                                    ep1, n_edges, nbuck, sgrid);
        subsort_kernel<<<nbuck, 1024, 0, stream>>>(ep1, base, rowsum, ep2);
        edge_mlp_mfma_kernel<<<egrid, block, 0, stream>>>(hh, w1t, ep2,
                                                          b1, W2, b2, out,
                                                          n_edges, egrid);
    } else if (ws_size >= hh_bytes) {
        __half* hh = (__half*)d_ws;
        convert_h_kernel<<<(n8 + block - 1) / block, block, 0, stream>>>(h, hh, n8);
        edge_mlp_fp16_kernel<<<egrid, block, 0, stream>>>(hh, src, dst,
                                                          W1, b1, W2, b2, out, n_edges);
    } else {
        edge_mlp_kernel<<<egrid, block, 0, stream>>>(h, src, dst,
                                                     W1, b1, W2, b2, out, n_edges);
    }
}